// Round 10
// baseline (121.438 us; speedup 1.0000x reference)
//
#include <hip/hip_runtime.h>
#include <hip/hip_bf16.h>
#include <math.h>

// MMD (InfoVAE RBF kernel), N=8192, D=128, fp32 in, scalar fp32 out.
//
// Round 20: r18 structure at FOUR waves/SIMD (register diet to 128
// unified). r19 post-mortem: A-in-regs halved the MFMA cover window
// (64x32 wave-tile: 8-MFMA ~150cy vs ~300cy L2 latency) and unified
// pressure hit ~176 anyway (compiler parked aAll in AGPRs) -> 56.8us.
// Reverted. Cross-round signature (r10-r19: 45-64us, MfmaUtil 24-30%,
// VALU 30-37%, nothing saturated, conflicts 0) = latency-bound at 12
// waves/CU. Lever not yet pulled on r18: OCCUPANCY.
//   Diet: r18 minus B-dbuf (single b[4]; LOADB(s+1) issues after
//   MFMAS(s) in program order - MFMA latches operands at issue, so the
//   ~300cy load flight rides under the ~310cy MFMA exec; compiler
//   handles the WAR hazard) minus segment-held ar (reload per tile,
//   L1-hot). VGPR ~ a16+b16+addr/temps20 = ~56 + acc 64 AGPR = ~120
//   unified <= 128 -> __launch_bounds__(256,4): 4 waves/SIMD, 16
//   waves/CU, 4 blocks/CU (LDS 33KB x4 = 132KB <= 160).
//   Grid: SPLIT=16 -> 64 pairs x 16 = 1024 blocks = 4/CU co-resident;
//   pair-balanced (129 tiles/pair) -> 8-9 tiles/block.
//   Everything else = r18 verbatim: A panel (4 planes x 8KB) DMA-staged
//   once per segment; J-loop barrier-free; B-frags direct from L2
//   (pre-swizzled plane layout: frag read = contiguous permuted 1KB);
//   per-element MFMA K-chain planes 0..3 ascending; epilogue formula
//   identical (passed 5.96e-8). Merged finish (done-ctr) kept from r19.

#define NN 8192
#define DD 128
#define TZ 16384
#define SPLIT 16
#define NBLK (64 * SPLIT)                  // 1024

typedef __attribute__((ext_vector_type(8))) short bf16x8;
typedef __attribute__((ext_vector_type(4))) float f32x4;
typedef __attribute__((ext_vector_type(2))) float f32x2;

#if __has_builtin(__builtin_amdgcn_exp2f)
#define EXP2F __builtin_amdgcn_exp2f
#else
#define EXP2F exp2f
#endif

constexpr float LOG2E = 0x1.715476p+0f;
constexpr float S2 = LOG2E / 8192.0f;              // 2*log2e/16384

constexpr size_t PLANE = 1048576;                  // 16384 rows x 64 B

#define LDS_RED 32768

// ---- ws layout ----
constexpr size_t WS_CTR  = 2048;
constexpr size_t WS_NORM = 2560;
constexpr size_t WS_Z    = WS_NORM + (size_t)TZ * sizeof(float);

__device__ __forceinline__ void gload_lds16(const void* g, void* l) {
  __builtin_amdgcn_global_load_lds(
      (const __attribute__((address_space(1))) void*)g,
      (__attribute__((address_space(3))) void*)l, 16, 0, 0);
}

__global__ __launch_bounds__(256) void prep(
    const float* __restrict__ X, const float* __restrict__ Y,
    char* __restrict__ Zs, float* __restrict__ normZ,
    double* __restrict__ sums, unsigned* __restrict__ ctr) {
  if (blockIdx.x == 0) {
    sums[threadIdx.x] = 0.0;                       // 256 slots
    if (threadIdx.x == 0) *ctr = 0u;
  }

  const int row = blockIdx.x * 4 + (threadIdx.x >> 6);
  const int lane = threadIdx.x & 63;
  const float* __restrict__ src =
      (row < NN) ? (X + (size_t)row * DD) : (Y + (size_t)(row - NN) * DD);
  const float2 v = *reinterpret_cast<const float2*>(src + 2 * lane);

  float n = v.x * v.x + v.y * v.y;

  // K-slice plane store, chunk pre-swizzled (r14-verified).
  const int ks = lane >> 4;
  const int quadc = (lane >> 2) & 3;
  const int inner = (lane & 3) * 4;
  char* dst = Zs + (size_t)ks * PLANE + (size_t)row * 64 +
              ((quadc ^ ((row >> 1) & 3)) << 4) + inner;
  *reinterpret_cast<__hip_bfloat162*>(dst) =
      __hip_bfloat162{__float2bfloat16(v.x), __float2bfloat16(v.y)};

#pragma unroll
  for (int o = 32; o > 0; o >>= 1) n += __shfl_down(n, o);
  if (lane == 0) normZ[row] = n * (-LOG2E / 16384.0f);  // pre-scaled
}

__global__ __launch_bounds__(256, 4) void mmd_mfma(
    const char* __restrict__ Zs, const float* __restrict__ normZ,
    double* __restrict__ sums, unsigned* __restrict__ ctr,
    float* __restrict__ out) {
  __shared__ alignas(16) char lds[LDS_RED + 64];   // A planes 4x8KB + red

  const int bid = blockIdx.x;
  const int p = bid / SPLIT, s = bid % SPLIT;
  const int q = 127 - p;
  const int n1 = (127 - p - s) / SPLIT + 1;        // strip p (>=1 always)
  const int u0 = s + SPLIT * n1 - (128 - p);       // in [0, SPLIT]
  const int n2 = (u0 <= p) ? (p - u0) / SPLIT + 1 : 0;

  const int segI[2]  = {p, q};
  const int segJ0[2] = {p + s, q + u0};
  const int segN[2]  = {n1, n2};

  const int tid = threadIdx.x;
  const int lane = tid & 63, wave = tid >> 6;      // 4 waves
  const int wr = wave >> 1, wc = wave & 1;         // 2x2: 64x64 per wave
  const int lr = lane & 15, quad = lane >> 4;

  // r13/r14-verified swizzle (identical on read & prep-store sides).
  const int csw = (quad ^ ((lr >> 1) & 3)) << 4;
  const char* aRd = lds + (wr * 64 + lr) * 64 + csw;
  const size_t bOff = (size_t)(wc * 64 + lr) * 64 + csw;

  bf16x8 a[4], b[4];

#define LOADA(ks) do {                                                      \
    _Pragma("unroll")                                                       \
    for (int i = 0; i < 4; ++i)                                             \
      a[i] = *reinterpret_cast<const bf16x8*>(aRd + (ks) * 8192 + i * 1024);\
  } while (0)

#define LOADB(base, pl) do {                                                \
    _Pragma("unroll")                                                       \
    for (int j = 0; j < 4; ++j)                                             \
      b[j] = *reinterpret_cast<const bf16x8*>(                              \
          (base) + (size_t)(pl) * PLANE + j * 1024);                        \
  } while (0)

#define MFMAS() do {                                                        \
    _Pragma("unroll")                                                       \
    for (int i = 0; i < 4; ++i)                                             \
      _Pragma("unroll")                                                     \
      for (int j = 0; j < 4; ++j)                                           \
        acc[i][j] = __builtin_amdgcn_mfma_f32_16x16x32_bf16(                \
            a[i], b[j], acc[i][j], 0, 0, 0);                                \
  } while (0)

  const f32x2 s2v = {S2, S2};
  double blockAcc = 0.0;

  for (int seg = 0; seg < 2; ++seg) {
    const int I = segI[seg];
    const int nIter = segN[seg];
    if (nIter == 0) continue;                      // block-uniform
    int J = segJ0[seg];

    // ---- stage A panel once: 4 planes x 8 KB, 2 issues/wave/plane ----
    const char* srcA0 = Zs + (size_t)(I * 128 + wave * 32) * 64 + lane * 16;
    char* ldwA = lds + wave * 2048;
#pragma unroll
    for (int ks = 0; ks < 4; ++ks) {
      gload_lds16(srcA0 + (size_t)ks * PLANE,        ldwA + ks * 8192);
      gload_lds16(srcA0 + (size_t)ks * PLANE + 1024, ldwA + ks * 8192 + 1024);
    }

    // First-tile plane-0 B preload (drained by the same vmcnt(0)).
    const char* bbase = Zs + (size_t)J * 8192 + bOff;
    LOADB(bbase, 0);
    asm volatile("s_waitcnt vmcnt(0)\n\ts_barrier" ::: "memory");

    const float* nzA = normZ + I * 128 + wr * 64;

    for (int it = 0; it < nIter; ++it) {
      const char* bnext = (it + 1 < nIter) ? bbase + SPLIT * 8192 : bbase;
      f32x4 acc[4][4] = {};

      // slice 0: compute with plane0 (preloaded); then fetch plane1
      LOADA(0);
      __builtin_amdgcn_sched_barrier(0);
      MFMAS();
      __builtin_amdgcn_sched_barrier(0);
      LOADB(bbase, 1);

      // slice 1
      LOADA(1);
      __builtin_amdgcn_sched_barrier(0);
      MFMAS();
      __builtin_amdgcn_sched_barrier(0);
      LOADB(bbase, 2);

      // slice 2
      LOADA(2);
      __builtin_amdgcn_sched_barrier(0);
      MFMAS();
      __builtin_amdgcn_sched_barrier(0);
      LOADB(bbase, 3);

      // slice 3; then prefetch NEXT tile plane0
      LOADA(3);
      __builtin_amdgcn_sched_barrier(0);
      MFMAS();
      __builtin_amdgcn_sched_barrier(0);
      LOADB(bnext, 0);

      // ---- epilogue: ar reloaded (L1-hot), cb direct ----
      f32x4 ar[4];
#pragma unroll
      for (int i = 0; i < 4; ++i)
        ar[i] = *reinterpret_cast<const f32x4*>(nzA + i * 16 + quad * 4);
      const float* nzB = normZ + J * 128 + wc * 64;
      float cb[4];
#pragma unroll
      for (int j = 0; j < 4; ++j) cb[j] = nzB[j * 16 + lr];

      f32x2 part01 = {0.f, 0.f}, part23 = {0.f, 0.f};
#pragma unroll
      for (int i = 0; i < 4; ++i) {
        const f32x2 ar01 = {ar[i].x, ar[i].y};
        const f32x2 ar23 = {ar[i].z, ar[i].w};
#pragma unroll
        for (int j = 0; j < 4; ++j) {
          const f32x2 rb2 = {cb[j], cb[j]};
          const f32x2 base01 = ar01 + rb2;
          const f32x2 base23 = ar23 + rb2;
          const f32x2 acc01 = {acc[i][j][0], acc[i][j][1]};
          const f32x2 acc23 = {acc[i][j][2], acc[i][j][3]};
          const f32x2 arg01 = __builtin_elementwise_fma(acc01, s2v, base01);
          const f32x2 arg23 = __builtin_elementwise_fma(acc23, s2v, base23);
          part01 += (f32x2){EXP2F(arg01.x), EXP2F(arg01.y)};
          part23 += (f32x2){EXP2F(arg23.x), EXP2F(arg23.y)};
        }
      }
      const f32x2 ps = part01 + part23;
      double w = ((I < 64) == (J < 64)) ? 1.0 : -1.0;  // X/Y boundary: 64
      if (I != J) w += w;
      blockAcc += (double)(ps.x + ps.y) * w;

      J += SPLIT;
      bbase = bnext;
    }

    // Segment end: all waves done reading A-LDS before next segment's DMA.
    __syncthreads();
  }

#undef LOADA
#undef LOADB
#undef MFMAS

  // ---- block reduce + merged finish ----
  __shared__ double red[4];
  __shared__ int lastFlag;
#pragma unroll
  for (int o = 32; o > 0; o >>= 1) blockAcc += __shfl_down(blockAcc, o);
  if (lane == 0) red[wave] = blockAcc;
  __syncthreads();
  if (tid == 0) {
    atomicAdd(&sums[bid & 255], red[0] + red[1] + red[2] + red[3]);
    __threadfence();
    lastFlag = (atomicAdd(ctr, 1u) == NBLK - 1);
  }
  __syncthreads();
  if (wave == 0 && lastFlag) {
    double v = 0.0;
#pragma unroll
    for (int k = 0; k < 4; ++k)
      v += atomicAdd(&sums[lane * 4 + k], 0.0);    // device-scope read
#pragma unroll
    for (int o = 32; o > 0; o >>= 1) v += __shfl_down(v, o);
    if (lane == 0)
      out[0] = (float)(v * (1.0 / ((double)NN * (double)NN)));
  }
}

extern "C" void kernel_launch(void* const* d_in, const int* in_sizes, int n_in,
                              void* d_out, int out_size, void* d_ws, size_t ws_size,
                              hipStream_t stream) {
  const float* y_inputs = (const float*)d_in[0];  // "inputs"
  const float* x_true   = (const float*)d_in[1];  // "true_samples"
  float* out = (float*)d_out;

  char* ws = (char*)d_ws;
  double* sums = (double*)ws;                     // 256 fp64 partial slots
  unsigned* ctr = (unsigned*)(ws + WS_CTR);
  float* normZ = (float*)(ws + WS_NORM);
  char* Zs = ws + WS_Z;

  prep<<<TZ / 4, 256, 0, stream>>>(x_true, y_inputs, Zs, normZ, sums, ctr);
  mmd_mfma<<<NBLK, 256, 0, stream>>>(Zs, normZ, sums, ctr, out);
}

// Round 13
// 110.360 us; speedup vs baseline: 1.1004x; 1.1004x over previous
//
#include <hip/hip_runtime.h>
#include <hip/hip_bf16.h>
#include <math.h>

// MMD (InfoVAE RBF kernel), N=8192, D=128, fp32 in, scalar fp32 out.
//
// Round 23: consolidation = r18 (best passing, 45.4us) + r19's merged
// finish (passing) + cross-tile DOUBLE B-prefetch (cover extension).
//   r21 post-mortem: 64-strip geometry -> 5-ulp drift, unexplained ->
//   parked (don't re-roll what you can't explain).
//   r22 post-mortem: cooperative fusion -> 3.6e-6; phase-2 was verbatim
//   r18, so the seam is cross-XCD visibility of phase-1 plain stores
//   (grid.sync != kernel-boundary writeback/invalidate for the
//   global_load_lds read path). The fix needs buffer_wbl2/buffer_inv,
//   absent from the ISA doc -> unverifiable -> fusion parked.
//   This round's one scheduling change (analytically safe): rotate each
//   slice's B-load to AFTER its MFMA cluster, so slice2/slice3 issue
//   BOTH next-tile planes 0,1 ahead of the ~900cy epilogue:
//     slice0: LOADA(0); MFMAS(b0=pl0); LOADB(b0, pl2)
//     slice1: LOADA(1); MFMAS(b1=pl1); LOADB(b1, pl3)
//     slice2: LOADA(2); MFMAS(b0=pl2); LOADB(b0, next pl0)
//     slice3: LOADA(3); MFMAS(b1=pl3); LOADB(b1, next pl1)
//   Covers: {pl0,pl1}: ~1200cy (epilogue+slice); {pl2,pl3}: ~310cy
//   (r18 had 1200/310/310/310). Same operand bytes, same MFMA order
//   (planes 0..3 ascending per element) -> accumulation bit-identical;
//   WAR (load overwrites buffer after its MFMAs issue) is enforced by
//   compiler register-dependency waitcnts. Only manual wait: one
//   vmcnt(0)+barrier after the per-segment A-DMA prologue.
//   Everything else r18 verbatim: pair-balanced triangle SPLIT=12
//   (768 blocks = 3/CU co-resident, 10-11 tiles/block), A panel
//   (4 planes x 8KB) DMA-staged once/segment, B direct L2->reg dbuf,
//   barrier-free J-loop, hoisted ar, epilogue formula (passed 5.96e-8).
//   Merged finish: r19's done-counter + device-scope atomicAdd(,0.0)
//   read-back (passed).

#define NN 8192
#define DD 128
#define TZ 16384
#define SPLIT 12
#define NBLK (64 * SPLIT)                  // 768

typedef __attribute__((ext_vector_type(8))) short bf16x8;
typedef __attribute__((ext_vector_type(4))) float f32x4;
typedef __attribute__((ext_vector_type(2))) float f32x2;

#if __has_builtin(__builtin_amdgcn_exp2f)
#define EXP2F __builtin_amdgcn_exp2f
#else
#define EXP2F exp2f
#endif

constexpr float LOG2E = 0x1.715476p+0f;
constexpr float S2 = LOG2E / 8192.0f;              // 2*log2e/16384

constexpr size_t PLANE = 1048576;                  // 16384 rows x 64 B

#define LDS_RED 32768

// ---- ws layout ----
constexpr size_t WS_CTR  = 2048;
constexpr size_t WS_NORM = 2560;
constexpr size_t WS_Z    = WS_NORM + (size_t)TZ * sizeof(float);

__device__ __forceinline__ void gload_lds16(const void* g, void* l) {
  __builtin_amdgcn_global_load_lds(
      (const __attribute__((address_space(1))) void*)g,
      (__attribute__((address_space(3))) void*)l, 16, 0, 0);
}

__global__ __launch_bounds__(256) void prep(
    const float* __restrict__ X, const float* __restrict__ Y,
    char* __restrict__ Zs, float* __restrict__ normZ,
    double* __restrict__ sums, unsigned* __restrict__ ctr) {
  if (blockIdx.x == 0) {
    sums[threadIdx.x] = 0.0;                       // 256 slots
    if (threadIdx.x == 0) *ctr = 0u;
  }

  const int row = blockIdx.x * 4 + (threadIdx.x >> 6);
  const int lane = threadIdx.x & 63;
  const float* __restrict__ src =
      (row < NN) ? (X + (size_t)row * DD) : (Y + (size_t)(row - NN) * DD);
  const float2 v = *reinterpret_cast<const float2*>(src + 2 * lane);

  float n = v.x * v.x + v.y * v.y;

  // K-slice plane store, chunk pre-swizzled (r14-verified).
  const int ks = lane >> 4;
  const int quadc = (lane >> 2) & 3;
  const int inner = (lane & 3) * 4;
  char* dst = Zs + (size_t)ks * PLANE + (size_t)row * 64 +
              ((quadc ^ ((row >> 1) & 3)) << 4) + inner;
  *reinterpret_cast<__hip_bfloat162*>(dst) =
      __hip_bfloat162{__float2bfloat16(v.x), __float2bfloat16(v.y)};

#pragma unroll
  for (int o = 32; o > 0; o >>= 1) n += __shfl_down(n, o);
  if (lane == 0) normZ[row] = n * (-LOG2E / 16384.0f);  // pre-scaled
}

__global__ __launch_bounds__(256, 3) void mmd_mfma(
    const char* __restrict__ Zs, const float* __restrict__ normZ,
    double* __restrict__ sums, unsigned* __restrict__ ctr,
    float* __restrict__ out) {
  __shared__ alignas(16) char lds[LDS_RED + 64];   // A planes 4x8KB + red

  const int bid = blockIdx.x;
  const int p = bid / SPLIT, s = bid % SPLIT;
  const int q = 127 - p;
  const int n1 = (127 - p - s) / SPLIT + 1;
  const int u0 = s + SPLIT * n1 - (128 - p);       // >= 0 by construction
  const int n2 = (u0 <= p) ? (p - u0) / SPLIT + 1 : 0;

  const int segI[2]  = {p, q};
  const int segJ0[2] = {p + s, q + u0};
  const int segN[2]  = {n1, n2};

  const int tid = threadIdx.x;
  const int lane = tid & 63, wave = tid >> 6;      // 4 waves
  const int wr = wave >> 1, wc = wave & 1;         // 2x2: 64x64 per wave
  const int lr = lane & 15, quad = lane >> 4;

  // r13/r14-verified swizzle (identical on read & prep-store sides).
  const int csw = (quad ^ ((lr >> 1) & 3)) << 4;
  const char* aRd = lds + (wr * 64 + lr) * 64 + csw;
  const size_t bOff = (size_t)(wc * 64 + lr) * 64 + csw;

  bf16x8 a[4], b0[4], b1[4];
  f32x4 ar[4];

#define LOADA(ks) do {                                                      \
    _Pragma("unroll")                                                       \
    for (int i = 0; i < 4; ++i)                                             \
      a[i] = *reinterpret_cast<const bf16x8*>(aRd + (ks) * 8192 + i * 1024);\
  } while (0)

#define LOADB(dst, base, pl) do {                                           \
    _Pragma("unroll")                                                       \
    for (int j = 0; j < 4; ++j)                                             \
      dst[j] = *reinterpret_cast<const bf16x8*>(                            \
          (base) + (size_t)(pl) * PLANE + j * 1024);                        \
  } while (0)

#define MFMAS(bb) do {                                                      \
    __builtin_amdgcn_s_setprio(1);                                          \
    _Pragma("unroll")                                                       \
    for (int i = 0; i < 4; ++i)                                             \
      _Pragma("unroll")                                                     \
      for (int j = 0; j < 4; ++j)                                           \
        acc[i][j] = __builtin_amdgcn_mfma_f32_16x16x32_bf16(                \
            a[i], bb[j], acc[i][j], 0, 0, 0);                               \
    __builtin_amdgcn_s_setprio(0);                                          \
  } while (0)

  const f32x2 s2v = {S2, S2};
  double blockAcc = 0.0;

  for (int seg = 0; seg < 2; ++seg) {
    const int I = segI[seg];
    const int nIter = segN[seg];
    if (nIter == 0) continue;                      // block-uniform
    int J = segJ0[seg];

    // ---- hoisted I-side norms ----
    const float* nzA = normZ + I * 128 + wr * 64;
#pragma unroll
    for (int i = 0; i < 4; ++i)
      ar[i] = *reinterpret_cast<const f32x4*>(nzA + i * 16 + quad * 4);

    // ---- stage A panel once: 4 planes x 8 KB, 2 issues/wave/plane ----
    const char* srcA0 = Zs + (size_t)(I * 128 + wave * 32) * 64 + lane * 16;
    char* ldwA = lds + wave * 2048;
#pragma unroll
    for (int ks = 0; ks < 4; ++ks) {
      gload_lds16(srcA0 + (size_t)ks * PLANE,        ldwA + ks * 8192);
      gload_lds16(srcA0 + (size_t)ks * PLANE + 1024, ldwA + ks * 8192 + 1024);
    }

    // First-tile planes 0,1 preload (drained by the same vmcnt(0)).
    const char* bbase = Zs + (size_t)J * 8192 + bOff;
    LOADB(b0, bbase, 0);
    LOADB(b1, bbase, 1);
    asm volatile("s_waitcnt vmcnt(0)\n\ts_barrier" ::: "memory");

    for (int it = 0; it < nIter; ++it) {
      const char* bnext = (it + 1 < nIter) ? bbase + SPLIT * 8192 : bbase;
      f32x4 acc[4][4] = {};

      // slice 0: compute pl0; then refill b0 <- pl2
      LOADA(0);
      __builtin_amdgcn_sched_barrier(0);
      MFMAS(b0);
      __builtin_amdgcn_sched_barrier(0);
      LOADB(b0, bbase, 2);

      // slice 1: compute pl1; then refill b1 <- pl3
      LOADA(1);
      __builtin_amdgcn_sched_barrier(0);
      MFMAS(b1);
      __builtin_amdgcn_sched_barrier(0);
      LOADB(b1, bbase, 3);

      // slice 2: compute pl2; then refill b0 <- NEXT tile pl0
      LOADA(2);
      __builtin_amdgcn_sched_barrier(0);
      MFMAS(b0);
      __builtin_amdgcn_sched_barrier(0);
      LOADB(b0, bnext, 0);

      // slice 3: compute pl3; then refill b1 <- NEXT tile pl1
      LOADA(3);
      __builtin_amdgcn_sched_barrier(0);
      MFMAS(b1);
      __builtin_amdgcn_sched_barrier(0);
      LOADB(b1, bnext, 1);

      // ---- epilogue: cb direct (L2-hot); exp2 + fp64 accumulate ----
      // (~900cy: covers the two next-tile B loads in flight.)
      const float* nzB = normZ + J * 128 + wc * 64;
      float cb[4];
#pragma unroll
      for (int j = 0; j < 4; ++j) cb[j] = nzB[j * 16 + lr];

      f32x2 part01 = {0.f, 0.f}, part23 = {0.f, 0.f};
#pragma unroll
      for (int i = 0; i < 4; ++i) {
        const f32x2 ar01 = {ar[i].x, ar[i].y};
        const f32x2 ar23 = {ar[i].z, ar[i].w};
#pragma unroll
        for (int j = 0; j < 4; ++j) {
          const f32x2 rb2 = {cb[j], cb[j]};
          const f32x2 base01 = ar01 + rb2;
          const f32x2 base23 = ar23 + rb2;
          const f32x2 acc01 = {acc[i][j][0], acc[i][j][1]};
          const f32x2 acc23 = {acc[i][j][2], acc[i][j][3]};
          const f32x2 arg01 = __builtin_elementwise_fma(acc01, s2v, base01);
          const f32x2 arg23 = __builtin_elementwise_fma(acc23, s2v, base23);
          part01 += (f32x2){EXP2F(arg01.x), EXP2F(arg01.y)};
          part23 += (f32x2){EXP2F(arg23.x), EXP2F(arg23.y)};
        }
      }
      const f32x2 ps = part01 + part23;
      double w = ((I < 64) == (J < 64)) ? 1.0 : -1.0;  // X/Y boundary: 64
      if (I != J) w += w;
      blockAcc += (double)(ps.x + ps.y) * w;

      J += SPLIT;
      bbase = bnext;
    }

    // Segment end: all waves done reading A-LDS before next segment's DMA.
    __syncthreads();
  }

#undef LOADA
#undef LOADB
#undef MFMAS

  // ---- block reduce + merged finish (r19-proven) ----
  __shared__ double red[4];
  __shared__ int lastFlag;
#pragma unroll
  for (int o = 32; o > 0; o >>= 1) blockAcc += __shfl_down(blockAcc, o);
  if (lane == 0) red[wave] = blockAcc;
  __syncthreads();
  if (tid == 0) {
    atomicAdd(&sums[bid & 255], red[0] + red[1] + red[2] + red[3]);
    __threadfence();
    lastFlag = (atomicAdd(ctr, 1u) == NBLK - 1);
  }
  __syncthreads();
  if (wave == 0 && lastFlag) {
    double v = 0.0;
#pragma unroll
    for (int k = 0; k < 4; ++k)
      v += atomicAdd(&sums[lane * 4 + k], 0.0);    // device-scope read
#pragma unroll
    for (int o = 32; o > 0; o >>= 1) v += __shfl_down(v, o);
    if (lane == 0)
      out[0] = (float)(v * (1.0 / ((double)NN * (double)NN)));
  }
}

extern "C" void kernel_launch(void* const* d_in, const int* in_sizes, int n_in,
                              void* d_out, int out_size, void* d_ws, size_t ws_size,
                              hipStream_t stream) {
  const float* y_inputs = (const float*)d_in[0];  // "inputs"
  const float* x_true   = (const float*)d_in[1];  // "true_samples"
  float* out = (float*)d_out;

  char* ws = (char*)d_ws;
  double* sums = (double*)ws;                     // 256 fp64 partial slots
  unsigned* ctr = (unsigned*)(ws + WS_CTR);
  float* normZ = (float*)(ws + WS_NORM);
  char* Zs = ws + WS_Z;

  prep<<<TZ / 4, 256, 0, stream>>>(x_true, y_inputs, Zs, normZ, sums, ctr);
  mmd_mfma<<<NBLK, 256, 0, stream>>>(Zs, normZ, sums, ctr, out);
}

// Round 14
// 110.341 us; speedup vs baseline: 1.1006x; 1.0002x over previous
//
#include <hip/hip_runtime.h>
#include <hip/hip_bf16.h>
#include <math.h>

// MMD (InfoVAE RBF kernel), N=8192, D=128, fp32 in, scalar fp32 out.
//
// Round 24: controlled experiment = r18 mmd loop VERBATIM (proven
// 45.4us / 5.96e-8) + r19's merged finish ONLY.
//   r23 post-mortem: rotating LOADB after MFMAS cost 12us (45.4->57.5):
//   in r18 the B vmem issue rides under the MFMA cluster's lgkm wait;
//   rotated, loads issue only after the cluster drains, and the
//   epilogue's cb loads (newer in the vmcnt queue) force a deeper
//   prefetch drain. Cover extension was the wrong trade. Reverted.
//   Remaining confound: every merged-finish round (r19/r20/r23) ran
//   >=56.8 while r18 (separate finish) ran 45.4 - each regression had
//   its own attributed cause, but the merge was never isolated. This
//   round isolates it: identical r18 hot loop, merge as the only delta.
//   - mmd ~45 -> merge free; total ~97 (gap shrank 57.8->52.9 in r23 =
//     ~5us/launch saved).
//   - mmd ~57 -> merge is the mechanism; revert next round.
//   Structure (r18): pair-balanced triangle SPLIT=12, 768 blocks = 3/CU
//   co-resident, 2 segments/block; A panel (4 planes x 8KB) DMA-staged
//   once/segment (vmcnt(0)+barrier only there); B fragments direct
//   L2->reg double-buffered, LOADB issued BEFORE each MFMA cluster;
//   barrier-free J-loop; hoisted ar; epilogue formula unchanged.
//   Numerics: element K-chain planes 0..3 ascending (pre-swizzled plane
//   layout, csw=(quad^((lr>>1)&3))<<4, measured 0 conflicts); fp32
//   partials <=16 terms; fp64 block acc; absmax expected 5.960464e-08.

#define NN 8192
#define DD 128
#define TZ 16384
#define SPLIT 12
#define NBLK (64 * SPLIT)                  // 768

typedef __attribute__((ext_vector_type(8))) short bf16x8;
typedef __attribute__((ext_vector_type(4))) float f32x4;
typedef __attribute__((ext_vector_type(2))) float f32x2;

#if __has_builtin(__builtin_amdgcn_exp2f)
#define EXP2F __builtin_amdgcn_exp2f
#else
#define EXP2F exp2f
#endif

constexpr float LOG2E = 0x1.715476p+0f;
constexpr float S2 = LOG2E / 8192.0f;              // 2*log2e/16384

constexpr size_t PLANE = 1048576;                  // 16384 rows x 64 B

#define LDS_RED 32768

// ---- ws layout ----
constexpr size_t WS_CTR  = 2048;
constexpr size_t WS_NORM = 2560;
constexpr size_t WS_Z    = WS_NORM + (size_t)TZ * sizeof(float);

__device__ __forceinline__ void gload_lds16(const void* g, void* l) {
  __builtin_amdgcn_global_load_lds(
      (const __attribute__((address_space(1))) void*)g,
      (__attribute__((address_space(3))) void*)l, 16, 0, 0);
}

__global__ __launch_bounds__(256) void prep(
    const float* __restrict__ X, const float* __restrict__ Y,
    char* __restrict__ Zs, float* __restrict__ normZ,
    double* __restrict__ sums, unsigned* __restrict__ ctr) {
  if (blockIdx.x == 0) {
    sums[threadIdx.x] = 0.0;                       // 256 slots
    if (threadIdx.x == 0) *ctr = 0u;
  }

  const int row = blockIdx.x * 4 + (threadIdx.x >> 6);
  const int lane = threadIdx.x & 63;
  const float* __restrict__ src =
      (row < NN) ? (X + (size_t)row * DD) : (Y + (size_t)(row - NN) * DD);
  const float2 v = *reinterpret_cast<const float2*>(src + 2 * lane);

  float n = v.x * v.x + v.y * v.y;

  // K-slice plane store, chunk pre-swizzled (r14-verified).
  const int ks = lane >> 4;
  const int quadc = (lane >> 2) & 3;
  const int inner = (lane & 3) * 4;
  char* dst = Zs + (size_t)ks * PLANE + (size_t)row * 64 +
              ((quadc ^ ((row >> 1) & 3)) << 4) + inner;
  *reinterpret_cast<__hip_bfloat162*>(dst) =
      __hip_bfloat162{__float2bfloat16(v.x), __float2bfloat16(v.y)};

#pragma unroll
  for (int o = 32; o > 0; o >>= 1) n += __shfl_down(n, o);
  if (lane == 0) normZ[row] = n * (-LOG2E / 16384.0f);  // pre-scaled
}

__global__ __launch_bounds__(256, 3) void mmd_mfma(
    const char* __restrict__ Zs, const float* __restrict__ normZ,
    double* __restrict__ sums, unsigned* __restrict__ ctr,
    float* __restrict__ out) {
  __shared__ alignas(16) char lds[LDS_RED + 64];   // A planes 4x8KB + red

  const int bid = blockIdx.x;
  const int p = bid / SPLIT, s = bid % SPLIT;
  const int q = 127 - p;
  const int n1 = (127 - p - s) / SPLIT + 1;
  const int u0 = s + SPLIT * n1 - (128 - p);       // >= 0 by construction
  const int n2 = (u0 <= p) ? (p - u0) / SPLIT + 1 : 0;

  const int segI[2]  = {p, q};
  const int segJ0[2] = {p + s, q + u0};
  const int segN[2]  = {n1, n2};

  const int tid = threadIdx.x;
  const int lane = tid & 63, wave = tid >> 6;      // 4 waves
  const int wr = wave >> 1, wc = wave & 1;         // 2x2: 64x64 per wave
  const int lr = lane & 15, quad = lane >> 4;

  // r13/r14-verified swizzle (identical on read & prep-store sides).
  const int csw = (quad ^ ((lr >> 1) & 3)) << 4;
  const char* aRd = lds + (wr * 64 + lr) * 64 + csw;
  const size_t bOff = (size_t)(wc * 64 + lr) * 64 + csw;

  bf16x8 a[4], b0[4], b1[4];
  f32x4 ar[4];

#define LOADA(ks) do {                                                      \
    _Pragma("unroll")                                                       \
    for (int i = 0; i < 4; ++i)                                             \
      a[i] = *reinterpret_cast<const bf16x8*>(aRd + (ks) * 8192 + i * 1024);\
  } while (0)

#define LOADB(dst, base, pl) do {                                           \
    _Pragma("unroll")                                                       \
    for (int j = 0; j < 4; ++j)                                             \
      dst[j] = *reinterpret_cast<const bf16x8*>(                            \
          (base) + (size_t)(pl) * PLANE + j * 1024);                        \
  } while (0)

#define MFMAS(bb) do {                                                      \
    __builtin_amdgcn_s_setprio(1);                                          \
    _Pragma("unroll")                                                       \
    for (int i = 0; i < 4; ++i)                                             \
      _Pragma("unroll")                                                     \
      for (int j = 0; j < 4; ++j)                                           \
        acc[i][j] = __builtin_amdgcn_mfma_f32_16x16x32_bf16(                \
            a[i], bb[j], acc[i][j], 0, 0, 0);                               \
    __builtin_amdgcn_s_setprio(0);                                          \
  } while (0)

  const f32x2 s2v = {S2, S2};
  double blockAcc = 0.0;

  for (int seg = 0; seg < 2; ++seg) {
    const int I = segI[seg];
    const int nIter = segN[seg];
    if (nIter == 0) continue;                      // block-uniform
    int J = segJ0[seg];

    // ---- hoisted I-side norms ----
    const float* nzA = normZ + I * 128 + wr * 64;
#pragma unroll
    for (int i = 0; i < 4; ++i)
      ar[i] = *reinterpret_cast<const f32x4*>(nzA + i * 16 + quad * 4);

    // ---- stage A panel once: 4 planes x 8 KB, 2 issues/wave/plane ----
    const char* srcA0 = Zs + (size_t)(I * 128 + wave * 32) * 64 + lane * 16;
    char* ldwA = lds + wave * 2048;
#pragma unroll
    for (int ks = 0; ks < 4; ++ks) {
      gload_lds16(srcA0 + (size_t)ks * PLANE,        ldwA + ks * 8192);
      gload_lds16(srcA0 + (size_t)ks * PLANE + 1024, ldwA + ks * 8192 + 1024);
    }

    // First-tile slice-0 B preload (drained by the same vmcnt(0)).
    const char* bbase = Zs + (size_t)J * 8192 + bOff;
    LOADB(b0, bbase, 0);
    asm volatile("s_waitcnt vmcnt(0)\n\ts_barrier" ::: "memory");

    for (int it = 0; it < nIter; ++it) {
      const char* bnext = (it + 1 < nIter) ? bbase + SPLIT * 8192 : bbase;
      f32x4 acc[4][4] = {};

      // slice 0: prefetch plane1 -> b1; compute with b0
      LOADB(b1, bbase, 1);
      LOADA(0);
      __builtin_amdgcn_sched_barrier(0);
      MFMAS(b0);

      // slice 1: prefetch plane2 -> b0; compute with b1
      LOADB(b0, bbase, 2);
      LOADA(1);
      __builtin_amdgcn_sched_barrier(0);
      MFMAS(b1);

      // slice 2: prefetch plane3 -> b1; compute with b0
      LOADB(b1, bbase, 3);
      LOADA(2);
      __builtin_amdgcn_sched_barrier(0);
      MFMAS(b0);

      // slice 3: prefetch NEXT tile plane0 -> b0; compute with b1
      LOADB(b0, bnext, 0);
      LOADA(3);
      __builtin_amdgcn_sched_barrier(0);
      MFMAS(b1);

      // ---- epilogue: cb direct (L2-hot); exp2 + fp64 accumulate ----
      const float* nzB = normZ + J * 128 + wc * 64;
      float cb[4];
#pragma unroll
      for (int j = 0; j < 4; ++j) cb[j] = nzB[j * 16 + lr];

      f32x2 part01 = {0.f, 0.f}, part23 = {0.f, 0.f};
#pragma unroll
      for (int i = 0; i < 4; ++i) {
        const f32x2 ar01 = {ar[i].x, ar[i].y};
        const f32x2 ar23 = {ar[i].z, ar[i].w};
#pragma unroll
        for (int j = 0; j < 4; ++j) {
          const f32x2 rb2 = {cb[j], cb[j]};
          const f32x2 base01 = ar01 + rb2;
          const f32x2 base23 = ar23 + rb2;
          const f32x2 acc01 = {acc[i][j][0], acc[i][j][1]};
          const f32x2 acc23 = {acc[i][j][2], acc[i][j][3]};
          const f32x2 arg01 = __builtin_elementwise_fma(acc01, s2v, base01);
          const f32x2 arg23 = __builtin_elementwise_fma(acc23, s2v, base23);
          part01 += (f32x2){EXP2F(arg01.x), EXP2F(arg01.y)};
          part23 += (f32x2){EXP2F(arg23.x), EXP2F(arg23.y)};
        }
      }
      const f32x2 ps = part01 + part23;
      double w = ((I < 64) == (J < 64)) ? 1.0 : -1.0;  // X/Y boundary: 64
      if (I != J) w += w;
      blockAcc += (double)(ps.x + ps.y) * w;

      J += SPLIT;
      bbase = bnext;
    }

    // Segment end: all waves done reading A-LDS before next segment's DMA.
    __syncthreads();
  }

#undef LOADA
#undef LOADB
#undef MFMAS

  // ---- block reduce + merged finish (r19-proven) ----
  __shared__ double red[4];
  __shared__ int lastFlag;
#pragma unroll
  for (int o = 32; o > 0; o >>= 1) blockAcc += __shfl_down(blockAcc, o);
  if (lane == 0) red[wave] = blockAcc;
  __syncthreads();
  if (tid == 0) {
    atomicAdd(&sums[bid & 255], red[0] + red[1] + red[2] + red[3]);
    __threadfence();
    lastFlag = (atomicAdd(ctr, 1u) == NBLK - 1);
  }
  __syncthreads();
  if (wave == 0 && lastFlag) {
    double v = 0.0;
#pragma unroll
    for (int k = 0; k < 4; ++k)
      v += atomicAdd(&sums[lane * 4 + k], 0.0);    // device-scope read
#pragma unroll
    for (int o = 32; o > 0; o >>= 1) v += __shfl_down(v, o);
    if (lane == 0)
      out[0] = (float)(v * (1.0 / ((double)NN * (double)NN)));
  }
}

extern "C" void kernel_launch(void* const* d_in, const int* in_sizes, int n_in,
                              void* d_out, int out_size, void* d_ws, size_t ws_size,
                              hipStream_t stream) {
  const float* y_inputs = (const float*)d_in[0];  // "inputs"
  const float* x_true   = (const float*)d_in[1];  // "true_samples"
  float* out = (float*)d_out;

  char* ws = (char*)d_ws;
  double* sums = (double*)ws;                     // 256 fp64 partial slots
  unsigned* ctr = (unsigned*)(ws + WS_CTR);
  float* normZ = (float*)(ws + WS_NORM);
  char* Zs = ws + WS_Z;

  prep<<<TZ / 4, 256, 0, stream>>>(x_true, y_inputs, Zs, normZ, sums, ctr);
  mmd_mfma<<<NBLK, 256, 0, stream>>>(Zs, normZ, sums, ctr, out);
}

// Round 15
// 100.561 us; speedup vs baseline: 1.2076x; 1.0973x over previous
//
#include <hip/hip_runtime.h>
#include <hip/hip_bf16.h>
#include <math.h>

// MMD (InfoVAE RBF kernel), N=8192, D=128, fp32 in, scalar fp32 out.
//
// Round 25 = r18 VERBATIM (best measured: mmd 45.4us, total 103.2us,
// absmax 5.960464e-08).
//   r24 post-mortem (merge isolation): mmd 54.2us BUT identical FETCH
//   bytes (17.47 GB) at exactly 1.19x lower HBM rate (360 vs 429 GB/s)
//   = uniform rate scaling on identical code -> SESSION CLOCK variance,
//   not a code effect. Corroboration: r23 vs r24 totals 110.36/110.34
//   (identical to 0.02%) despite r23's rotation "regression" story.
//   Cross-session comparisons without within-probe A/B chased noise
//   (guide rule #13). What survives: fixed gap total-mmd ~54-58us in
//   EVERY round (launch count / merged finish move it <=2us); mmd
//   structure family = 45-60us session-scaled across 10 structural
//   variants; cooperative fusion of the fixed cost is blocked by the
//   XCD-coherence seam (r22: grid.sync does not writeback/invalidate
//   the global_load_lds read path).
//   This submission recovers the proven-best configuration exactly.
//
// r18 design (best passing): B direct from L2 into register dbuf;
// A-only in LDS; zero per-tile barriers; r17 triangle-paired balance.
//   - Pair strip p with 127-p: 129 tiles/pair constant; SPLIT=12 ->
//     768 blocks = 3/CU co-resident, 10-11 tiles/block, 2 segments.
//   - A panel (4 planes x 8 KB) DMA-staged once per segment
//     (global_load_lds, contiguous pre-swizzled 1-KB issues); single
//     vmcnt(0)+barrier after staging; barrier-free J-loop.
//   - B fragments direct L2->reg, double-buffered one slice ahead,
//     cross-tile prefetch during slice 3 (in the pre-swizzled K-plane
//     layout a B-fragment read = one contiguous permuted 1-KB block).
//   - Epilogue: k = exp2(acc*S2 + ra + rb), ra/rb pre-scaled by
//     -log2e/16384; fp32 partials (<=16 terms); fp64 block accumulate;
//     sign by X/Y boundary (tile 64), x2 off-diagonal.
//   Numerics: element K-chain = 4x mfma_16x16x32_bf16 planes 0..3
//   ascending; plane layout pre-swizzles chunk c^((row>>1)&3) at prep
//   store; read csw=(quad^((lr>>1)&3))<<4 (measured 0 bank conflicts).

#define NN 8192
#define DD 128
#define TZ 16384
#define SPLIT 12
#define NBLK (64 * SPLIT)                  // 768

typedef __attribute__((ext_vector_type(8))) short bf16x8;
typedef __attribute__((ext_vector_type(4))) float f32x4;
typedef __attribute__((ext_vector_type(2))) float f32x2;

#if __has_builtin(__builtin_amdgcn_exp2f)
#define EXP2F __builtin_amdgcn_exp2f
#else
#define EXP2F exp2f
#endif

constexpr float LOG2E = 0x1.715476p+0f;
constexpr float S2 = LOG2E / 8192.0f;              // 2*log2e/16384

constexpr size_t PLANE = 1048576;                  // 16384 rows x 64 B

#define LDS_RED 32768

// ---- ws layout ----
constexpr size_t WS_NORM = 2048;                   // sums: 256 fp64 slots
constexpr size_t WS_Z    = WS_NORM + (size_t)TZ * sizeof(float);

__device__ __forceinline__ void gload_lds16(const void* g, void* l) {
  __builtin_amdgcn_global_load_lds(
      (const __attribute__((address_space(1))) void*)g,
      (__attribute__((address_space(3))) void*)l, 16, 0, 0);
}

__global__ __launch_bounds__(256) void prep(
    const float* __restrict__ X, const float* __restrict__ Y,
    char* __restrict__ Zs, float* __restrict__ normZ,
    double* __restrict__ sums) {
  if (blockIdx.x == 0) sums[threadIdx.x] = 0.0;    // 256 slots

  const int row = blockIdx.x * 4 + (threadIdx.x >> 6);
  const int lane = threadIdx.x & 63;
  const float* __restrict__ src =
      (row < NN) ? (X + (size_t)row * DD) : (Y + (size_t)(row - NN) * DD);
  const float2 v = *reinterpret_cast<const float2*>(src + 2 * lane);

  float n = v.x * v.x + v.y * v.y;

  // K-slice plane store, chunk pre-swizzled (r14-verified).
  const int ks = lane >> 4;
  const int quadc = (lane >> 2) & 3;
  const int inner = (lane & 3) * 4;
  char* dst = Zs + (size_t)ks * PLANE + (size_t)row * 64 +
              ((quadc ^ ((row >> 1) & 3)) << 4) + inner;
  *reinterpret_cast<__hip_bfloat162*>(dst) =
      __hip_bfloat162{__float2bfloat16(v.x), __float2bfloat16(v.y)};

#pragma unroll
  for (int o = 32; o > 0; o >>= 1) n += __shfl_down(n, o);
  if (lane == 0) normZ[row] = n * (-LOG2E / 16384.0f);  // pre-scaled
}

__global__ __launch_bounds__(256, 3) void mmd_mfma(
    const char* __restrict__ Zs, const float* __restrict__ normZ,
    double* __restrict__ sums) {
  __shared__ alignas(16) char lds[LDS_RED + 64];   // A planes 4x8KB + red

  const int bid = blockIdx.x;
  const int p = bid / SPLIT, s = bid % SPLIT;
  const int q = 127 - p;
  const int n1 = (127 - p - s) / SPLIT + 1;
  const int u0 = s + SPLIT * n1 - (128 - p);       // >= 0 by construction
  const int n2 = (u0 <= p) ? (p - u0) / SPLIT + 1 : 0;

  const int segI[2]  = {p, q};
  const int segJ0[2] = {p + s, q + u0};
  const int segN[2]  = {n1, n2};

  const int tid = threadIdx.x;
  const int lane = tid & 63, wave = tid >> 6;      // 4 waves
  const int wr = wave >> 1, wc = wave & 1;         // 2x2: 64x64 per wave
  const int lr = lane & 15, quad = lane >> 4;

  // r13/r14-verified swizzle (identical on read & prep-store sides).
  const int csw = (quad ^ ((lr >> 1) & 3)) << 4;
  const char* aRd = lds + (wr * 64 + lr) * 64 + csw;
  const size_t bOff = (size_t)(wc * 64 + lr) * 64 + csw;

  bf16x8 a[4], b0[4], b1[4];
  f32x4 ar[4];

#define LOADA(ks) do {                                                      \
    _Pragma("unroll")                                                       \
    for (int i = 0; i < 4; ++i)                                             \
      a[i] = *reinterpret_cast<const bf16x8*>(aRd + (ks) * 8192 + i * 1024);\
  } while (0)

#define LOADB(dst, base, pl) do {                                           \
    _Pragma("unroll")                                                       \
    for (int j = 0; j < 4; ++j)                                             \
      dst[j] = *reinterpret_cast<const bf16x8*>(                            \
          (base) + (size_t)(pl) * PLANE + j * 1024);                        \
  } while (0)

#define MFMAS(bb) do {                                                      \
    __builtin_amdgcn_s_setprio(1);                                          \
    _Pragma("unroll")                                                       \
    for (int i = 0; i < 4; ++i)                                             \
      _Pragma("unroll")                                                     \
      for (int j = 0; j < 4; ++j)                                           \
        acc[i][j] = __builtin_amdgcn_mfma_f32_16x16x32_bf16(                \
            a[i], bb[j], acc[i][j], 0, 0, 0);                               \
    __builtin_amdgcn_s_setprio(0);                                          \
  } while (0)

  const f32x2 s2v = {S2, S2};
  double blockAcc = 0.0;

  for (int seg = 0; seg < 2; ++seg) {
    const int I = segI[seg];
    const int nIter = segN[seg];
    if (nIter == 0) continue;                      // block-uniform
    int J = segJ0[seg];

    // ---- hoisted I-side norms ----
    const float* nzA = normZ + I * 128 + wr * 64;
#pragma unroll
    for (int i = 0; i < 4; ++i)
      ar[i] = *reinterpret_cast<const f32x4*>(nzA + i * 16 + quad * 4);

    // ---- stage A panel once: 4 planes x 8 KB, 2 issues/wave/plane ----
    const char* srcA0 = Zs + (size_t)(I * 128 + wave * 32) * 64 + lane * 16;
    char* ldwA = lds + wave * 2048;
#pragma unroll
    for (int ks = 0; ks < 4; ++ks) {
      gload_lds16(srcA0 + (size_t)ks * PLANE,        ldwA + ks * 8192);
      gload_lds16(srcA0 + (size_t)ks * PLANE + 1024, ldwA + ks * 8192 + 1024);
    }

    // First-tile slice-0 B preload (drained by the same vmcnt(0)).
    const char* bbase = Zs + (size_t)J * 8192 + bOff;
    LOADB(b0, bbase, 0);
    asm volatile("s_waitcnt vmcnt(0)\n\ts_barrier" ::: "memory");

    for (int it = 0; it < nIter; ++it) {
      const char* bnext = (it + 1 < nIter) ? bbase + SPLIT * 8192 : bbase;
      f32x4 acc[4][4] = {};

      // slice 0: prefetch plane1 -> b1; compute with b0
      LOADB(b1, bbase, 1);
      LOADA(0);
      __builtin_amdgcn_sched_barrier(0);
      MFMAS(b0);

      // slice 1: prefetch plane2 -> b0; compute with b1
      LOADB(b0, bbase, 2);
      LOADA(1);
      __builtin_amdgcn_sched_barrier(0);
      MFMAS(b1);

      // slice 2: prefetch plane3 -> b1; compute with b0
      LOADB(b1, bbase, 3);
      LOADA(2);
      __builtin_amdgcn_sched_barrier(0);
      MFMAS(b0);

      // slice 3: prefetch NEXT tile plane0 -> b0; compute with b1
      LOADB(b0, bnext, 0);
      LOADA(3);
      __builtin_amdgcn_sched_barrier(0);
      MFMAS(b1);

      // ---- epilogue: cb direct (L2-hot); exp2 + fp64 accumulate ----
      const float* nzB = normZ + J * 128 + wc * 64;
      float cb[4];
#pragma unroll
      for (int j = 0; j < 4; ++j) cb[j] = nzB[j * 16 + lr];

      f32x2 part01 = {0.f, 0.f}, part23 = {0.f, 0.f};
#pragma unroll
      for (int i = 0; i < 4; ++i) {
        const f32x2 ar01 = {ar[i].x, ar[i].y};
        const f32x2 ar23 = {ar[i].z, ar[i].w};
#pragma unroll
        for (int j = 0; j < 4; ++j) {
          const f32x2 rb2 = {cb[j], cb[j]};
          const f32x2 base01 = ar01 + rb2;
          const f32x2 base23 = ar23 + rb2;
          const f32x2 acc01 = {acc[i][j][0], acc[i][j][1]};
          const f32x2 acc23 = {acc[i][j][2], acc[i][j][3]};
          const f32x2 arg01 = __builtin_elementwise_fma(acc01, s2v, base01);
          const f32x2 arg23 = __builtin_elementwise_fma(acc23, s2v, base23);
          part01 += (f32x2){EXP2F(arg01.x), EXP2F(arg01.y)};
          part23 += (f32x2){EXP2F(arg23.x), EXP2F(arg23.y)};
        }
      }
      const f32x2 ps = part01 + part23;
      double w = ((I < 64) == (J < 64)) ? 1.0 : -1.0;  // X/Y boundary: 64
      if (I != J) w += w;
      blockAcc += (double)(ps.x + ps.y) * w;

      J += SPLIT;
      bbase = bnext;
    }

    // Segment end: all waves done reading A-LDS before next segment's DMA.
    __syncthreads();
  }

#undef LOADA
#undef LOADB
#undef MFMAS

#pragma unroll
  for (int o = 32; o > 0; o >>= 1) blockAcc += __shfl_down(blockAcc, o);
  double* red = reinterpret_cast<double*>(lds + LDS_RED);
  if (lane == 0) red[wave] = blockAcc;
  __syncthreads();
  if (tid == 0)
    atomicAdd(&sums[bid & 255], red[0] + red[1] + red[2] + red[3]);
}

__global__ void finish(const double* __restrict__ s, float* __restrict__ out) {
  double v = s[threadIdx.x] + s[threadIdx.x + 64] + s[threadIdx.x + 128] +
             s[threadIdx.x + 192];
#pragma unroll
  for (int o = 32; o > 0; o >>= 1) v += __shfl_down(v, o);
  if (threadIdx.x == 0)
    out[0] = (float)(v * (1.0 / ((double)NN * (double)NN)));
}

extern "C" void kernel_launch(void* const* d_in, const int* in_sizes, int n_in,
                              void* d_out, int out_size, void* d_ws, size_t ws_size,
                              hipStream_t stream) {
  const float* y_inputs = (const float*)d_in[0];  // "inputs"
  const float* x_true   = (const float*)d_in[1];  // "true_samples"
  float* out = (float*)d_out;

  char* ws = (char*)d_ws;
  double* sums = (double*)ws;                     // 256 fp64 partial slots
  float* normZ = (float*)(ws + WS_NORM);
  char* Zs = ws + WS_Z;

  prep<<<TZ / 4, 256, 0, stream>>>(x_true, y_inputs, Zs, normZ, sums);
  mmd_mfma<<<NBLK, 256, 0, stream>>>(Zs, normZ, sums);
  finish<<<1, 64, 0, stream>>>(sums, out);
}